// Round 8
// baseline (385.701 us; speedup 1.0000x reference)
//
#include <hip/hip_runtime.h>
#include <cstdint>
#include <cstddef>
#include <cmath>

// ClipLoss fused: loss = mean_i( 0.5*(lse_row_i + lse_col_i) - diag_i )
// logits = SCALE * img @ txt^T. Stats in exp2 domain: fp8 img copy is
// pre-scaled by CF = SCALE*log2(e); lse_nat = ln2 * (m + log2(s)).
//
// R8: MX fp8 GEMM with half-granule-plane layout. A'/B' stored e4m3 as
// [p][row][16 B], p = k/16 (32 planes over K=512). Staging: 1 KB contiguous
// global -> LDS plane (lp*128 + row)*16. Fragment = two ds_read_b128 from
// planes quad*2, quad*2+1: 8 consecutive rows x 16 B = all 32 banks ->
// conflict-free. K-loop: 4 x BK=128 16x16x128 f8f6f4 MFMA, unit E8M0 scales.

#define N_ROWS 16384
#define DIM    512
#define NB     128
#define SCALE  14.285714285714286f
#define CF     20.609929155556625f   // SCALE * log2(e)
#define LN2F   0.6931471805599453f
#define SP     36                    // part[] row stride in floats (144 B)
#define CVP    528                   // cvt LDS row stride in bytes

typedef __attribute__((ext_vector_type(8))) int   int8v;
typedef __attribute__((ext_vector_type(4))) int   int4v;
typedef __attribute__((ext_vector_type(4))) float floatx4;

#if __has_builtin(__builtin_amdgcn_exp2f)
#define EXP2(x) __builtin_amdgcn_exp2f(x)
#else
#define EXP2(x) exp2f(x)
#endif

// ---------------------------------------------------------------- helpers ---
__device__ __forceinline__ void async_load16(const void* g, void* l) {
    __builtin_amdgcn_global_load_lds(
        (__attribute__((address_space(1))) void*)(void*)(g),
        (__attribute__((address_space(3))) void*)(l), 16, 0, 0);
}

__device__ __forceinline__ void lse_merge2(float& m, float& s, float om, float os) {
    float nm = fmaxf(m, om);
    s = s * EXP2(m - nm) + os * EXP2(om - nm);
    m = nm;
}

// pack 4 floats -> 4 e4m3 bytes in one i32 (RNE, OCP on gfx950)
__device__ __forceinline__ int pk_fp8x4(float a, float b, float c, float d) {
    int u = __builtin_amdgcn_cvt_pk_fp8_f32(a, b, 0, false);
    u = __builtin_amdgcn_cvt_pk_fp8_f32(c, d, u, true);
    return u;
}

// --------------------------------------------- cvt + swizzle + diag ---------
// Block handles 16 rows. Phase 1 (r = t>>4, gg = t&15): lane reads 32 fp32
// (128 B; 16 lanes cover 2 KB contiguous), converts to 32 fp8, stores to LDS
// row-major (stride CVP). Diag partial dot reduced via quarter-wave shfl.
// Phase 2 (row = t&15, p = t>>4 then +16): writes plane pieces
// [p][row][16 B]; 16 lanes cover 256 B contiguous per piece-column.
__global__ void cvt_diag_kernel(const float* __restrict__ a, const float* __restrict__ b,
                                unsigned char* __restrict__ A8, unsigned char* __restrict__ B8,
                                float* __restrict__ diag) {
    __shared__ __align__(16) unsigned char la[16 * CVP];
    __shared__ __align__(16) unsigned char lb[16 * CVP];
    const int t = threadIdx.x;
    const int rb = blockIdx.x * 16;

    {
        const int r = t >> 4, gg = t & 15;
        const float4* ai = (const float4*)(a + (size_t)(rb + r) * DIM + gg * 32);
        const float4* bi = (const float4*)(b + (size_t)(rb + r) * DIM + gg * 32);
        float dot = 0.f;
        int wa[8], wb[8];
#pragma unroll
        for (int j = 0; j < 4; ++j) {
            float4 x0 = ai[2 * j], x1 = ai[2 * j + 1];
            float4 y0 = bi[2 * j], y1 = bi[2 * j + 1];
            dot += x0.x * y0.x + x0.y * y0.y + x0.z * y0.z + x0.w * y0.w
                 + x1.x * y1.x + x1.y * y1.y + x1.z * y1.z + x1.w * y1.w;
            wa[2 * j]     = pk_fp8x4(CF * x0.x, CF * x0.y, CF * x0.z, CF * x0.w);
            wa[2 * j + 1] = pk_fp8x4(CF * x1.x, CF * x1.y, CF * x1.z, CF * x1.w);
            wb[2 * j]     = pk_fp8x4(y0.x, y0.y, y0.z, y0.w);
            wb[2 * j + 1] = pk_fp8x4(y1.x, y1.y, y1.z, y1.w);
        }
        *(int4v*)(la + r * CVP + gg * 32)      = (int4v){wa[0], wa[1], wa[2], wa[3]};
        *(int4v*)(la + r * CVP + gg * 32 + 16) = (int4v){wa[4], wa[5], wa[6], wa[7]};
        *(int4v*)(lb + r * CVP + gg * 32)      = (int4v){wb[0], wb[1], wb[2], wb[3]};
        *(int4v*)(lb + r * CVP + gg * 32 + 16) = (int4v){wb[4], wb[5], wb[6], wb[7]};
        dot += __shfl_xor(dot, 1);
        dot += __shfl_xor(dot, 2);
        dot += __shfl_xor(dot, 4);
        dot += __shfl_xor(dot, 8);
        if (gg == 0) diag[rb + r] = SCALE * dot;
    }
    __syncthreads();

    {
        const int row = t & 15;
#pragma unroll
        for (int hh = 0; hh < 2; ++hh) {
            const int p = (t >> 4) + hh * 16;      // 16-B k-piece, p = k/16
            int4v va = *(const int4v*)(la + row * CVP + p * 16);
            int4v vb = *(const int4v*)(lb + row * CVP + p * 16);
            const size_t o = ((size_t)p * N_ROWS + rb + row) * 16;
            *(int4v*)(A8 + o) = va;
            *(int4v*)(B8 + o) = vb;
        }
    }
}

// --------------------------------------------------- fused GEMM + LSE -------
__global__ void gemm_lse_kernel(const unsigned char* __restrict__ A8,
                                const unsigned char* __restrict__ B8,
                                float* __restrict__ row_m, float* __restrict__ row_s,
                                float* __restrict__ col_m, float* __restrict__ col_s) {
    __shared__ __align__(16) unsigned char smem[32768];
    unsigned char* sA = smem;            // 8 planes x 128 rows x 16 B = 16 KB
    unsigned char* sB = smem + 16384;    // 16 KB
    float* part = (float*)smem;          // [128][SP] = 18432 B overlay

    const int t = threadIdx.x;
    const int bid = blockIdx.x;

    // XCD-aware swizzle: each XCD owns a 16-row A band (L2-resident), sweeps bc
    const int xcd   = bid & 7;
    const int local = bid >> 3;
    const int br    = xcd * 16 + (local & 15);
    const int bc    = local >> 4;

    const int lane = t & 63;
    const int w    = t >> 6;
    const int quad = lane >> 4;
    const int l15  = lane & 15;
    const int wrow = w >> 1;
    const int wcol = w & 1;

    floatx4 acc[4][4];
#pragma unroll
    for (int i = 0; i < 4; ++i)
#pragma unroll
        for (int j = 0; j < 4; ++j)
            acc[i][j] = (floatx4){0.f, 0.f, 0.f, 0.f};

    // staging: waves 0,1 -> A planes {0..3},{4..7}; waves 2,3 -> B likewise.
    // piece c: lp = pbase + (c>>1), rh = c&1. One instr = 64 rows x 16 B = 1 KB
    // contiguous global -> contiguous LDS.
    const int isB   = w >> 1;
    const int pbase = (w & 1) * 4;
    const unsigned char* gsrc = isB ? B8 : A8;
    const int rbase = (isB ? bc : br) * 128;
    unsigned char* lbase = isB ? sB : sA;

    const unsigned char* gp[8];
    unsigned char* lp[8];
#pragma unroll
    for (int c = 0; c < 8; ++c) {
        const int pl = pbase + (c >> 1), rh = c & 1;
        gp[c] = gsrc + ((size_t)pl * N_ROWS + rbase + rh * 64 + lane) * 16;
        lp[c] = lbase + (pl * 128 + rh * 64) * 16;
    }
    const size_t kbstr = (size_t)8 * N_ROWS * 16;   // bytes per kb step (8 planes)

    for (int kb = 0; kb < 4; ++kb) {
        const size_t ko = (size_t)kb * kbstr;
#pragma unroll
        for (int c = 0; c < 8; ++c) async_load16(gp[c] + ko, lp[c]);
        __builtin_amdgcn_s_waitcnt(0);
        __syncthreads();

        int8v av[4], bv[4];
#pragma unroll
        for (int mi = 0; mi < 4; ++mi) {
            const int row = wrow * 64 + mi * 16 + l15;
            int4v lo = *(const int4v*)(sA + ((quad * 2) * 128 + row) * 16);
            int4v hi = *(const int4v*)(sA + ((quad * 2 + 1) * 128 + row) * 16);
            av[mi] = (int8v){lo[0], lo[1], lo[2], lo[3], hi[0], hi[1], hi[2], hi[3]};
        }
#pragma unroll
        for (int ni = 0; ni < 4; ++ni) {
            const int row = wcol * 64 + ni * 16 + l15;
            int4v lo = *(const int4v*)(sB + ((quad * 2) * 128 + row) * 16);
            int4v hi = *(const int4v*)(sB + ((quad * 2 + 1) * 128 + row) * 16);
            bv[ni] = (int8v){lo[0], lo[1], lo[2], lo[3], hi[0], hi[1], hi[2], hi[3]};
        }
#pragma unroll
        for (int mi = 0; mi < 4; ++mi)
#pragma unroll
            for (int ni = 0; ni < 4; ++ni)
                acc[mi][ni] = __builtin_amdgcn_mfma_scale_f32_16x16x128_f8f6f4(
                    av[mi], bv[ni], acc[mi][ni], 0, 0, 0, 127, 0, 127);
        __syncthreads();
    }

    // ---- epilogue. C/D layout (16x16): col = lane&15, row = quad*4 + reg. ----
    // lane holds rows lrow = wrow*64+mi*16+quad*4+r, cols wcol*64+ni*16+l15.

    // phase A1: row partial max (over ni) -> part[lrow][wcol*16+l15]
#pragma unroll
    for (int mi = 0; mi < 4; ++mi)
#pragma unroll
        for (int r = 0; r < 4; ++r) {
            float pm = fmaxf(fmaxf(acc[mi][0][r], acc[mi][1][r]),
                             fmaxf(acc[mi][2][r], acc[mi][3][r]));
            int lrow = wrow * 64 + mi * 16 + quad * 4 + r;
            part[lrow * SP + wcol * 16 + l15] = pm;
        }

    // phase A2: col stats (shfl over quads) -> part[cl][32..35]
#pragma unroll
    for (int ni = 0; ni < 4; ++ni) {
        float m = acc[0][ni][0];
#pragma unroll
        for (int mi = 0; mi < 4; ++mi)
#pragma unroll
            for (int r = 0; r < 4; ++r)
                m = fmaxf(m, acc[mi][ni][r]);
        m = fmaxf(m, __shfl_xor(m, 16));
        m = fmaxf(m, __shfl_xor(m, 32));
        float s = 0.f;
#pragma unroll
        for (int mi = 0; mi < 4; ++mi)
#pragma unroll
            for (int r = 0; r < 4; ++r)
                s += EXP2(acc[mi][ni][r] - m);
        s += __shfl_xor(s, 16);
        s += __shfl_xor(s, 32);
        if (quad == 0) {
            int cl = wcol * 64 + ni * 16 + l15;
            part[cl * SP + 32 + wrow] = m;   // 32,33
            part[cl * SP + 34 + wrow] = s;   // 34,35
        }
    }
    __syncthreads();

    if (t < 128) {
        // finish cols: merge wrow halves, store
        float m = part[t * SP + 32], s = part[t * SP + 34];
        lse_merge2(m, s, part[t * SP + 33], part[t * SP + 35]);
        col_m[(size_t)br * N_ROWS + bc * 128 + t] = m;
        col_s[(size_t)br * N_ROWS + bc * 128 + t] = s;
        // row max over 32 partials (8 x float4, stride 144 B)
        const float4* p4 = (const float4*)&part[t * SP];
        float4 v = p4[0];
#pragma unroll
        for (int j = 1; j < 8; ++j) {
            float4 u = p4[j];
            v.x = fmaxf(v.x, u.x); v.y = fmaxf(v.y, u.y);
            v.z = fmaxf(v.z, u.z); v.w = fmaxf(v.w, u.w);
        }
        part[t * SP + 32] = fmaxf(fmaxf(v.x, v.y), fmaxf(v.z, v.w));
    }
    __syncthreads();

    // phase B: row partial sums with broadcast max
#pragma unroll
    for (int mi = 0; mi < 4; ++mi)
#pragma unroll
        for (int r = 0; r < 4; ++r) {
            int lrow = wrow * 64 + mi * 16 + quad * 4 + r;
            float m = part[lrow * SP + 32];
            float s = EXP2(acc[mi][0][r] - m) + EXP2(acc[mi][1][r] - m)
                    + EXP2(acc[mi][2][r] - m) + EXP2(acc[mi][3][r] - m);
            part[lrow * SP + wcol * 16 + l15] = s;
        }
    __syncthreads();

    if (t < 128) {
        const float4* p4 = (const float4*)&part[t * SP];
        float4 v = p4[0];
#pragma unroll
        for (int j = 1; j < 8; ++j) {
            float4 u = p4[j];
            v.x += u.x; v.y += u.y; v.z += u.z; v.w += u.w;
        }
        float s = (v.x + v.y) + (v.z + v.w);
        float m = part[t * SP + 32];
        row_m[(size_t)bc * N_ROWS + br * 128 + t] = m;
        row_s[(size_t)bc * N_ROWS + br * 128 + t] = s;
    }
}

// --------------------------------------------------------- final reduce -----
__global__ void reduce_kernel(const float* __restrict__ row_m, const float* __restrict__ row_s,
                              const float* __restrict__ col_m, const float* __restrict__ col_s,
                              const float* __restrict__ diag, float* __restrict__ out) {
    const int w = threadIdx.x >> 6, lane = threadIdx.x & 63;
    const int row = blockIdx.x * 64 + lane;
    const size_t jt0 = (size_t)w * 32;

    float m = row_m[jt0 * N_ROWS + row];
    float s = row_s[jt0 * N_ROWS + row];
    for (int k = 1; k < 32; ++k)
        lse_merge2(m, s, row_m[(jt0 + k) * N_ROWS + row], row_s[(jt0 + k) * N_ROWS + row]);
    float mc = col_m[jt0 * N_ROWS + row];
    float sc = col_s[jt0 * N_ROWS + row];
    for (int k = 1; k < 32; ++k)
        lse_merge2(mc, sc, col_m[(jt0 + k) * N_ROWS + row], col_s[(jt0 + k) * N_ROWS + row]);

    __shared__ float sm[4][64], ss[4][64], tm[4][64], ts[4][64];
    sm[w][lane] = m;  ss[w][lane] = s;
    tm[w][lane] = mc; ts[w][lane] = sc;
    __syncthreads();

    if (w == 0) {
#pragma unroll
        for (int h = 1; h < 4; ++h) lse_merge2(m, s, sm[h][lane], ss[h][lane]);
        float lse_r = m + log2f(s);
#pragma unroll
        for (int h = 1; h < 4; ++h) lse_merge2(mc, sc, tm[h][lane], ts[h][lane]);
        float lse_c = mc + log2f(sc);
        float contrib = 0.5f * LN2F * (lse_r + lse_c) - diag[row];
        for (int mask = 32; mask; mask >>= 1) contrib += __shfl_xor(contrib, mask);
        if (lane == 0) atomicAdd(out, contrib * (1.0f / N_ROWS));
    }
}

// -------------------------------------------------------------- launch ------
extern "C" void kernel_launch(void* const* d_in, const int* in_sizes, int n_in,
                              void* d_out, int out_size, void* d_ws, size_t ws_size,
                              hipStream_t stream) {
    const float* img = (const float*)d_in[0];
    const float* txt = (const float*)d_in[1];
    char* ws = (char*)d_ws;

    const size_t MB = 1024 * 1024;
    unsigned char* A8 = (unsigned char*)(ws);                   // 8 MB fp8 swizzled CF*img
    unsigned char* B8 = (unsigned char*)(ws + 8 * MB);          // 8 MB fp8 swizzled txt
    float* row_m = (float*)(ws + 16 * MB);                      // 8 MB
    float* row_s = (float*)(ws + 24 * MB);                      // 8 MB
    float* col_m = (float*)(ws + 32 * MB);                      // 8 MB
    float* col_s = (float*)(ws + 40 * MB);                      // 8 MB
    float* diag  = (float*)(ws + 48 * MB);                      // 64 KB
    float* out   = (float*)d_out;

    hipMemsetAsync(d_out, 0, sizeof(float), stream);
    cvt_diag_kernel<<<N_ROWS / 16, 256, 0, stream>>>(img, txt, A8, B8, diag);
    gemm_lse_kernel<<<NB * NB, 256, 0, stream>>>(A8, B8, row_m, row_s, col_m, col_s);
    reduce_kernel<<<N_ROWS / 64, 256, 0, stream>>>(row_m, row_s, col_m, col_s, diag, out);
}

// Round 9
// 339.192 us; speedup vs baseline: 1.1371x; 1.1371x over previous
//
#include <hip/hip_runtime.h>
#include <cstdint>
#include <cstddef>
#include <cmath>

// ClipLoss fused: loss = mean_i( 0.5*(lse_row_i + lse_col_i) - diag_i )
// logits = SCALE * img @ txt^T. Stats in exp2 domain: fp8 img copy is
// pre-scaled by CF = SCALE*log2(e); lse_nat = ln2 * (m + log2(s)).
//
// R9: MX fp8 GEMM, tile-contiguous global layout. A'/B' stored e4m3 as
// [tile][p][r7][16 B]: tile = row/128 (64 KB contiguous per tile),
// p = k/16 (32 planes x 2 KB), r7 = row%128. Staging streams each tile
// sequentially (1 KB contiguous per instr, 8 KB per wave per kb) into the
// k-chunked LDS plane layout (pl*128+row)*16 -> conflict-free ds_read_b128
// fragments. K-loop: 4 x BK=128 16x16x128 f8f6f4 MFMA, unit E8M0 scales.

#define N_ROWS 16384
#define DIM    512
#define NB     128
#define SCALE  14.285714285714286f
#define CF     20.609929155556625f   // SCALE * log2(e)
#define LN2F   0.6931471805599453f
#define SP     36                    // part[] row stride in floats (144 B)
#define CVP    528                   // cvt LDS row stride in bytes
#define TILEB  65536                 // bytes per 128-row tile (32 planes x 2 KB)

typedef __attribute__((ext_vector_type(8))) int   int8v;
typedef __attribute__((ext_vector_type(4))) int   int4v;
typedef __attribute__((ext_vector_type(4))) float floatx4;

#if __has_builtin(__builtin_amdgcn_exp2f)
#define EXP2(x) __builtin_amdgcn_exp2f(x)
#else
#define EXP2(x) exp2f(x)
#endif

// ---------------------------------------------------------------- helpers ---
__device__ __forceinline__ void async_load16(const void* g, void* l) {
    __builtin_amdgcn_global_load_lds(
        (__attribute__((address_space(1))) void*)(void*)(g),
        (__attribute__((address_space(3))) void*)(l), 16, 0, 0);
}

__device__ __forceinline__ void lse_merge2(float& m, float& s, float om, float os) {
    float nm = fmaxf(m, om);
    s = s * EXP2(m - nm) + os * EXP2(om - nm);
    m = nm;
}

// pack 4 floats -> 4 e4m3 bytes in one i32 (RNE, OCP on gfx950)
__device__ __forceinline__ int pk_fp8x4(float a, float b, float c, float d) {
    int u = __builtin_amdgcn_cvt_pk_fp8_f32(a, b, 0, false);
    u = __builtin_amdgcn_cvt_pk_fp8_f32(c, d, u, true);
    return u;
}

// --------------------------------------------- cvt + swizzle + diag ---------
// Block handles 16 rows (within one 128-row tile). Phase 1: lane (r=t>>4,
// gg=t&15) reads 32 fp32 (128 B), converts to fp8, stores to LDS row-major.
// Phase 2: writes tile-contiguous pieces [tile][p][r7][16 B].
__global__ void cvt_diag_kernel(const float* __restrict__ a, const float* __restrict__ b,
                                unsigned char* __restrict__ A8, unsigned char* __restrict__ B8,
                                float* __restrict__ diag) {
    __shared__ __align__(16) unsigned char la[16 * CVP];
    __shared__ __align__(16) unsigned char lb[16 * CVP];
    const int t = threadIdx.x;
    const int rb = blockIdx.x * 16;

    {
        const int r = t >> 4, gg = t & 15;
        const float4* ai = (const float4*)(a + (size_t)(rb + r) * DIM + gg * 32);
        const float4* bi = (const float4*)(b + (size_t)(rb + r) * DIM + gg * 32);
        float dot = 0.f;
        int wa[8], wb[8];
#pragma unroll
        for (int j = 0; j < 4; ++j) {
            float4 x0 = ai[2 * j], x1 = ai[2 * j + 1];
            float4 y0 = bi[2 * j], y1 = bi[2 * j + 1];
            dot += x0.x * y0.x + x0.y * y0.y + x0.z * y0.z + x0.w * y0.w
                 + x1.x * y1.x + x1.y * y1.y + x1.z * y1.z + x1.w * y1.w;
            wa[2 * j]     = pk_fp8x4(CF * x0.x, CF * x0.y, CF * x0.z, CF * x0.w);
            wa[2 * j + 1] = pk_fp8x4(CF * x1.x, CF * x1.y, CF * x1.z, CF * x1.w);
            wb[2 * j]     = pk_fp8x4(y0.x, y0.y, y0.z, y0.w);
            wb[2 * j + 1] = pk_fp8x4(y1.x, y1.y, y1.z, y1.w);
        }
        *(int4v*)(la + r * CVP + gg * 32)      = (int4v){wa[0], wa[1], wa[2], wa[3]};
        *(int4v*)(la + r * CVP + gg * 32 + 16) = (int4v){wa[4], wa[5], wa[6], wa[7]};
        *(int4v*)(lb + r * CVP + gg * 32)      = (int4v){wb[0], wb[1], wb[2], wb[3]};
        *(int4v*)(lb + r * CVP + gg * 32 + 16) = (int4v){wb[4], wb[5], wb[6], wb[7]};
        dot += __shfl_xor(dot, 1);
        dot += __shfl_xor(dot, 2);
        dot += __shfl_xor(dot, 4);
        dot += __shfl_xor(dot, 8);
        if (gg == 0) diag[rb + r] = SCALE * dot;
    }
    __syncthreads();

    {
        const int row = t & 15;
        const size_t tbase = (size_t)(rb >> 7) * TILEB;
        const int r7 = (rb & 127) + row;
#pragma unroll
        for (int hh = 0; hh < 2; ++hh) {
            const int p = (t >> 4) + hh * 16;      // 16-B k-piece, p = k/16
            int4v va = *(const int4v*)(la + row * CVP + p * 16);
            int4v vb = *(const int4v*)(lb + row * CVP + p * 16);
            const size_t o = tbase + (size_t)p * 2048 + (size_t)r7 * 16;
            *(int4v*)(A8 + o) = va;
            *(int4v*)(B8 + o) = vb;
        }
    }
}

// --------------------------------------------------- fused GEMM + LSE -------
__global__ void gemm_lse_kernel(const unsigned char* __restrict__ A8,
                                const unsigned char* __restrict__ B8,
                                float* __restrict__ row_m, float* __restrict__ row_s,
                                float* __restrict__ col_m, float* __restrict__ col_s) {
    __shared__ __align__(16) unsigned char smem[32768];
    unsigned char* sA = smem;            // 8 planes x 128 rows x 16 B = 16 KB
    unsigned char* sB = smem + 16384;    // 16 KB
    float* part = (float*)smem;          // [128][SP] = 18432 B overlay

    const int t = threadIdx.x;
    const int bid = blockIdx.x;

    // XCD-aware swizzle: each XCD owns a 16-row A band (L2-resident), sweeps bc
    const int xcd   = bid & 7;
    const int local = bid >> 3;
    const int br    = xcd * 16 + (local & 15);
    const int bc    = local >> 4;

    const int lane = t & 63;
    const int w    = t >> 6;
    const int quad = lane >> 4;
    const int l15  = lane & 15;
    const int wrow = w >> 1;
    const int wcol = w & 1;

    floatx4 acc[4][4];
#pragma unroll
    for (int i = 0; i < 4; ++i)
#pragma unroll
        for (int j = 0; j < 4; ++j)
            acc[i][j] = (floatx4){0.f, 0.f, 0.f, 0.f};

    // staging: waves 0,1 -> A planes {0..3},{4..7}; waves 2,3 -> B likewise.
    // piece c: pl = pbase + (c>>1), rh = c&1; one instr = 1 KB contiguous
    // within the tile's sequential 64 KB.
    const int isB   = w >> 1;
    const int pbase = (w & 1) * 4;
    const unsigned char* tsrc = (isB ? B8 : A8) + (size_t)(isB ? bc : br) * TILEB;
    unsigned char* lbase = isB ? sB : sA;

    const unsigned char* gp[8];
    unsigned char* lp[8];
#pragma unroll
    for (int c = 0; c < 8; ++c) {
        const int pl = pbase + (c >> 1), rh = c & 1;
        gp[c] = tsrc + (size_t)pl * 2048 + (rh * 64 + lane) * 16;
        lp[c] = lbase + (pl * 128 + rh * 64) * 16;
    }

    for (int kb = 0; kb < 4; ++kb) {
        const size_t ko = (size_t)kb * 16384;   // 8 planes x 2 KB per kb
#pragma unroll
        for (int c = 0; c < 8; ++c) async_load16(gp[c] + ko, lp[c]);
        __builtin_amdgcn_s_waitcnt(0);
        __syncthreads();

        int8v av[4], bv[4];
#pragma unroll
        for (int mi = 0; mi < 4; ++mi) {
            const int row = wrow * 64 + mi * 16 + l15;
            int4v lo = *(const int4v*)(sA + ((quad * 2) * 128 + row) * 16);
            int4v hi = *(const int4v*)(sA + ((quad * 2 + 1) * 128 + row) * 16);
            av[mi] = (int8v){lo[0], lo[1], lo[2], lo[3], hi[0], hi[1], hi[2], hi[3]};
        }
#pragma unroll
        for (int ni = 0; ni < 4; ++ni) {
            const int row = wcol * 64 + ni * 16 + l15;
            int4v lo = *(const int4v*)(sB + ((quad * 2) * 128 + row) * 16);
            int4v hi = *(const int4v*)(sB + ((quad * 2 + 1) * 128 + row) * 16);
            bv[ni] = (int8v){lo[0], lo[1], lo[2], lo[3], hi[0], hi[1], hi[2], hi[3]};
        }
#pragma unroll
        for (int mi = 0; mi < 4; ++mi)
#pragma unroll
            for (int ni = 0; ni < 4; ++ni)
                acc[mi][ni] = __builtin_amdgcn_mfma_scale_f32_16x16x128_f8f6f4(
                    av[mi], bv[ni], acc[mi][ni], 0, 0, 0, 127, 0, 127);
        __syncthreads();
    }

    // ---- epilogue. C/D layout (16x16): col = lane&15, row = quad*4 + reg. ----
    // lane holds rows lrow = wrow*64+mi*16+quad*4+r, cols wcol*64+ni*16+l15.

    // phase A1: row partial max (over ni) -> part[lrow][wcol*16+l15]
#pragma unroll
    for (int mi = 0; mi < 4; ++mi)
#pragma unroll
        for (int r = 0; r < 4; ++r) {
            float pm = fmaxf(fmaxf(acc[mi][0][r], acc[mi][1][r]),
                             fmaxf(acc[mi][2][r], acc[mi][3][r]));
            int lrow = wrow * 64 + mi * 16 + quad * 4 + r;
            part[lrow * SP + wcol * 16 + l15] = pm;
        }

    // phase A2: col stats (shfl over quads) -> part[cl][32..35]
#pragma unroll
    for (int ni = 0; ni < 4; ++ni) {
        float m = acc[0][ni][0];
#pragma unroll
        for (int mi = 0; mi < 4; ++mi)
#pragma unroll
            for (int r = 0; r < 4; ++r)
                m = fmaxf(m, acc[mi][ni][r]);
        m = fmaxf(m, __shfl_xor(m, 16));
        m = fmaxf(m, __shfl_xor(m, 32));
        float s = 0.f;
#pragma unroll
        for (int mi = 0; mi < 4; ++mi)
#pragma unroll
            for (int r = 0; r < 4; ++r)
                s += EXP2(acc[mi][ni][r] - m);
        s += __shfl_xor(s, 16);
        s += __shfl_xor(s, 32);
        if (quad == 0) {
            int cl = wcol * 64 + ni * 16 + l15;
            part[cl * SP + 32 + wrow] = m;   // 32,33
            part[cl * SP + 34 + wrow] = s;   // 34,35
        }
    }
    __syncthreads();

    if (t < 128) {
        // finish cols: merge wrow halves, store
        float m = part[t * SP + 32], s = part[t * SP + 34];
        lse_merge2(m, s, part[t * SP + 33], part[t * SP + 35]);
        col_m[(size_t)br * N_ROWS + bc * 128 + t] = m;
        col_s[(size_t)br * N_ROWS + bc * 128 + t] = s;
        // row max over 32 partials (8 x float4, stride 144 B)
        const float4* p4 = (const float4*)&part[t * SP];
        float4 v = p4[0];
#pragma unroll
        for (int j = 1; j < 8; ++j) {
            float4 u = p4[j];
            v.x = fmaxf(v.x, u.x); v.y = fmaxf(v.y, u.y);
            v.z = fmaxf(v.z, u.z); v.w = fmaxf(v.w, u.w);
        }
        part[t * SP + 32] = fmaxf(fmaxf(v.x, v.y), fmaxf(v.z, v.w));
    }
    __syncthreads();

    // phase B: row partial sums with broadcast max
#pragma unroll
    for (int mi = 0; mi < 4; ++mi)
#pragma unroll
        for (int r = 0; r < 4; ++r) {
            int lrow = wrow * 64 + mi * 16 + quad * 4 + r;
            float m = part[lrow * SP + 32];
            float s = EXP2(acc[mi][0][r] - m) + EXP2(acc[mi][1][r] - m)
                    + EXP2(acc[mi][2][r] - m) + EXP2(acc[mi][3][r] - m);
            part[lrow * SP + wcol * 16 + l15] = s;
        }
    __syncthreads();

    if (t < 128) {
        const float4* p4 = (const float4*)&part[t * SP];
        float4 v = p4[0];
#pragma unroll
        for (int j = 1; j < 8; ++j) {
            float4 u = p4[j];
            v.x += u.x; v.y += u.y; v.z += u.z; v.w += u.w;
        }
        float s = (v.x + v.y) + (v.z + v.w);
        float m = part[t * SP + 32];
        row_m[(size_t)bc * N_ROWS + br * 128 + t] = m;
        row_s[(size_t)bc * N_ROWS + br * 128 + t] = s;
    }
}

// --------------------------------------------------------- final reduce -----
__global__ void reduce_kernel(const float* __restrict__ row_m, const float* __restrict__ row_s,
                              const float* __restrict__ col_m, const float* __restrict__ col_s,
                              const float* __restrict__ diag, float* __restrict__ out) {
    const int w = threadIdx.x >> 6, lane = threadIdx.x & 63;
    const int row = blockIdx.x * 64 + lane;
    const size_t jt0 = (size_t)w * 32;

    float m = row_m[jt0 * N_ROWS + row];
    float s = row_s[jt0 * N_ROWS + row];
    for (int k = 1; k < 32; ++k)
        lse_merge2(m, s, row_m[(jt0 + k) * N_ROWS + row], row_s[(jt0 + k) * N_ROWS + row]);
    float mc = col_m[jt0 * N_ROWS + row];
    float sc = col_s[jt0 * N_ROWS + row];
    for (int k = 1; k < 32; ++k)
        lse_merge2(mc, sc, col_m[(jt0 + k) * N_ROWS + row], col_s[(jt0 + k) * N_ROWS + row]);

    __shared__ float sm[4][64], ss[4][64], tm[4][64], ts[4][64];
    sm[w][lane] = m;  ss[w][lane] = s;
    tm[w][lane] = mc; ts[w][lane] = sc;
    __syncthreads();

    if (w == 0) {
#pragma unroll
        for (int h = 1; h < 4; ++h) lse_merge2(m, s, sm[h][lane], ss[h][lane]);
        float lse_r = m + log2f(s);
#pragma unroll
        for (int h = 1; h < 4; ++h) lse_merge2(mc, sc, tm[h][lane], ts[h][lane]);
        float lse_c = mc + log2f(sc);
        float contrib = 0.5f * LN2F * (lse_r + lse_c) - diag[row];
        for (int mask = 32; mask; mask >>= 1) contrib += __shfl_xor(contrib, mask);
        if (lane == 0) atomicAdd(out, contrib * (1.0f / N_ROWS));
    }
}

// -------------------------------------------------------------- launch ------
extern "C" void kernel_launch(void* const* d_in, const int* in_sizes, int n_in,
                              void* d_out, int out_size, void* d_ws, size_t ws_size,
                              hipStream_t stream) {
    const float* img = (const float*)d_in[0];
    const float* txt = (const float*)d_in[1];
    char* ws = (char*)d_ws;

    const size_t MB = 1024 * 1024;
    unsigned char* A8 = (unsigned char*)(ws);                   // 8 MB fp8 tiled CF*img
    unsigned char* B8 = (unsigned char*)(ws + 8 * MB);          // 8 MB fp8 tiled txt
    float* row_m = (float*)(ws + 16 * MB);                      // 8 MB
    float* row_s = (float*)(ws + 24 * MB);                      // 8 MB
    float* col_m = (float*)(ws + 32 * MB);                      // 8 MB
    float* col_s = (float*)(ws + 40 * MB);                      // 8 MB
    float* diag  = (float*)(ws + 48 * MB);                      // 64 KB
    float* out   = (float*)d_out;

    hipMemsetAsync(d_out, 0, sizeof(float), stream);
    cvt_diag_kernel<<<N_ROWS / 16, 256, 0, stream>>>(img, txt, A8, B8, diag);
    gemm_lse_kernel<<<NB * NB, 256, 0, stream>>>(A8, B8, row_m, row_s, col_m, col_s);
    reduce_kernel<<<N_ROWS / 64, 256, 0, stream>>>(row_m, row_s, col_m, col_s, diag, out);
}